// Round 3
// baseline (4278.264 us; speedup 1.0000x reference)
//
#include <hip/hip_runtime.h>

#define BB 4
#define HH 20
#define DHD 64
#define DD 1280
#define DFFN 5120
#define VV 8000
#define HIST 1024
#define TENC 512
#define KVLEN 1025
#define NLAYER 16

// ---------------- output offsets (floats) ----------------
// new_k: (L,B,H,DH,1025) ; new_v: (L,B,H,1025,DH) ; logits (4,8000) ; kv (1)
static const size_t NK_OFF = 0;
static const size_t NV_OFF = 83968000ull;              // 16*4*20*64*1025
static const size_t LG_OFF = 167936000ull;
static const size_t KV_IDX = 167968000ull;

// ---------------- kernels ----------------

__global__ __launch_bounds__(256) void embed_kernel(
    const float* __restrict__ emb, const float* __restrict__ pe,
    const int* __restrict__ ids, float* __restrict__ x) {
    int i = blockIdx.x * 256 + threadIdx.x;   // B*D = 5120
    if (i >= BB * DD) return;
    int b = i / DD, d = i % DD;
    int tok = ids[b];                          // S=1
    x[i] = emb[(size_t)tok * DD + d] + pe[(size_t)HIST * DD + d];
}

// finalize residual (x += rbias + sum_j pin[j]) then LayerNorm -> xn.  grid=B, block=256
__global__ __launch_bounds__(256) void ln_fin(
    float* __restrict__ x, const float* __restrict__ pin, int np,
    const float* __restrict__ rbias,
    const float* __restrict__ lw, const float* __restrict__ lb,
    float* __restrict__ xn) {
    int b = blockIdx.x, tid = threadIdx.x;
    __shared__ float vbuf[DD];
    __shared__ float red[256];
    float* xb = x + b * DD;
    for (int i = tid; i < DD; i += 256) {
        float v = xb[i];
        if (rbias) v += rbias[i];
        for (int j = 0; j < np; ++j) v += pin[(size_t)(j * BB + b) * DD + i];
        xb[i] = v;
        vbuf[i] = v;
    }
    __syncthreads();
    float s = 0.f;
    for (int i = tid; i < DD; i += 256) s += vbuf[i];
    red[tid] = s; __syncthreads();
    for (int st = 128; st > 0; st >>= 1) { if (tid < st) red[tid] += red[tid + st]; __syncthreads(); }
    float mean = red[0] / DD; __syncthreads();
    float vs = 0.f;
    for (int i = tid; i < DD; i += 256) { float d = vbuf[i] - mean; vs += d * d; }
    red[tid] = vs; __syncthreads();
    for (int st = 128; st > 0; st >>= 1) { if (tid < st) red[tid] += red[tid + st]; __syncthreads(); }
    float rstd = rsqrtf(red[0] / DD + 1e-5f);
    for (int i = tid; i < DD; i += 256)
        xn[b * DD + i] = (vbuf[i] - mean) * rstd * lw[i] + lb[i];
}

// QKV (or cross-q) partial GEMV.  grid=(H, nmat*4), block=256 (4 row-groups x 64 lanes).
// out layout: [(mat*4+rc)][h][b][64]
__global__ __launch_bounds__(256) void qkv_part_k(
    const float* __restrict__ w0, const float* __restrict__ w1p, const float* __restrict__ w2p,
    const float* __restrict__ xn, float* __restrict__ outp) {
    int h = blockIdx.x;
    int mat = blockIdx.y >> 2, rc = blockIdx.y & 3;
    const float* W = (mat == 0 ? w0 : mat == 1 ? w1p : w2p) + (size_t)h * DD * DHD;
    int tid = threadIdx.x, g = tid >> 6, lane = tid & 63;
    __shared__ float acts[BB * 320];
    __shared__ float red[4][4][64];
    int row0 = rc * 320;
    for (int i = tid; i < BB * 320; i += 256) {
        int b = i / 320, r = i % 320;
        acts[i] = xn[b * DD + row0 + r];
    }
    __syncthreads();
    float a0 = 0, a1 = 0, a2 = 0, a3 = 0;
    const float* Wg = W + (size_t)(row0 + g * 80) * DHD + lane;
    const float* ag = acts + g * 80;
#pragma unroll 4
    for (int r = 0; r < 80; ++r) {
        float w = Wg[(size_t)r * DHD];
        a0 += ag[r] * w;
        a1 += ag[320 + r] * w;
        a2 += ag[640 + r] * w;
        a3 += ag[960 + r] * w;
    }
    red[g][0][lane] = a0; red[g][1][lane] = a1; red[g][2][lane] = a2; red[g][3][lane] = a3;
    __syncthreads();
    if (g == 0) {
        for (int b = 0; b < BB; ++b) {
            float v = red[0][b][lane] + red[1][b][lane] + red[2][b][lane] + red[3][b][lane];
            outp[(size_t)(((mat * 4 + rc) * HH + h) * BB + b) * 64 + lane] = v;
        }
    }
}

// self-attention chunk pass + fused cache->output copy.
// grid=(H,B,4) block=256.  stats[(b*H+h)*4+c] = {m, sumexp, pv[64]}
__global__ __launch_bounds__(256) void attn_self_A(
    const float* __restrict__ kc, const float* __restrict__ vc,
    const float* __restrict__ qkvp, const float* __restrict__ bq_l,
    const float* __restrict__ mflagp,
    float* __restrict__ nk, float* __restrict__ nv, float* __restrict__ stats) {
    int h = blockIdx.x, b = blockIdx.y, c = blockIdx.z;
    int tid = threadIdx.x;
    __shared__ float qs[64];
    __shared__ float parr[256];
    __shared__ float red[256];
    __shared__ float pvred[4][64];
    if (tid < 64) {
        float qv = bq_l[h * 64 + tid];
        for (int rc = 0; rc < 4; ++rc)
            qv += qkvp[(size_t)((rc * HH + h) * BB + b) * 64 + tid];
        qs[tid] = qv;
    }
    __syncthreads();
    int j = c * 256 + tid;
    const float* kb = kc + ((size_t)(b * HH + h) * DHD) * HIST + j;
    float* nkb = nk + ((size_t)(b * HH + h) * DHD) * KVLEN + j;
    float sc = 0.f;
#pragma unroll 8
    for (int dh = 0; dh < 64; ++dh) {
        float kvv = kb[(size_t)dh * HIST];
        nkb[(size_t)dh * KVLEN] = kvv;
        sc += qs[dh] * kvv;
    }
    if (j != 0) sc += -128.0f * mflagp[0];
    red[tid] = sc; __syncthreads();
    for (int st = 128; st > 0; st >>= 1) { if (tid < st) red[tid] = fmaxf(red[tid], red[tid + st]); __syncthreads(); }
    float m = red[0]; __syncthreads();
    float p = expf(sc - m);
    parr[tid] = p;
    red[tid] = p; __syncthreads();
    for (int st = 128; st > 0; st >>= 1) { if (tid < st) red[tid] += red[tid + st]; __syncthreads(); }
    float ssum = red[0];
    int g = tid >> 6, lane = tid & 63;
    const float* vb = vc + ((size_t)(b * HH + h) * HIST) * DHD;
    float* nvb = nv + ((size_t)(b * HH + h) * KVLEN) * DHD;
    float acc = 0.f;
#pragma unroll 4
    for (int i = g; i < 256; i += 4) {
        size_t jj = (size_t)(c * 256 + i);
        float vv = vb[jj * DHD + lane];
        nvb[jj * DHD + lane] = vv;
        acc += parr[i] * vv;
    }
    pvred[g][lane] = acc; __syncthreads();
    float* st_ = stats + (size_t)((b * HH + h) * 4 + c) * 66;
    if (tid == 0) { st_[0] = m; st_[1] = ssum; }
    if (g == 0) st_[2 + lane] = pvred[0][lane] + pvred[1][lane] + pvred[2][lane] + pvred[3][lane];
}

// combine chunks + new kv element.  grid=(H,B) block=64
__global__ __launch_bounds__(64) void attn_self_B(
    const float* __restrict__ qkvp, const float* __restrict__ bq_l,
    const float* __restrict__ bv_l, const float* __restrict__ mflagp,
    const float* __restrict__ stats,
    float* __restrict__ nk, float* __restrict__ nv, float* __restrict__ aout) {
    int h = blockIdx.x, b = blockIdx.y, lane = threadIdx.x;
    float q = bq_l[h * 64 + lane], kn = 0.f, vn = bv_l[h * 64 + lane];
    for (int rc = 0; rc < 4; ++rc) {
        q  += qkvp[(size_t)((( 0 + rc) * HH + h) * BB + b) * 64 + lane];
        kn += qkvp[(size_t)((( 4 + rc) * HH + h) * BB + b) * 64 + lane];
        vn += qkvp[(size_t)((( 8 + rc) * HH + h) * BB + b) * 64 + lane];
    }
    float* nkb = nk + ((size_t)(b * HH + h) * DHD) * KVLEN;
    float* nvb = nv + ((size_t)(b * HH + h) * KVLEN) * DHD;
    nkb[(size_t)lane * KVLEN + HIST] = kn;
    nvb[(size_t)HIST * DHD + lane] = vn;
    float sn = q * kn;
    for (int off = 32; off > 0; off >>= 1) sn += __shfl_xor(sn, off, 64);
    sn += -128.0f * mflagp[0];
    const float* st0 = stats + (size_t)((b * HH + h) * 4) * 66;
    float m0 = st0[0], m1 = st0[66], m2 = st0[132], m3 = st0[198];
    float M = fmaxf(fmaxf(fmaxf(m0, m1), fmaxf(m2, m3)), sn);
    float e0 = expf(m0 - M), e1 = expf(m1 - M), e2 = expf(m2 - M), e3 = expf(m3 - M), en = expf(sn - M);
    float denom = e0 * st0[1] + e1 * st0[67] + e2 * st0[133] + e3 * st0[199] + en;
    float num = e0 * st0[2 + lane] + e1 * st0[68 + lane] + e2 * st0[134 + lane] + e3 * st0[200 + lane] + en * vn;
    aout[(b * HH + h) * 64 + lane] = num / denom;
}

// cross-attention chunk pass. grid=(H,B,2) block=256
__global__ __launch_bounds__(256) void attn_cross_A(
    const float* __restrict__ ckl, const float* __restrict__ cvl,
    const float* __restrict__ qkvp, const float* __restrict__ cbq_l,
    float* __restrict__ stats) {
    int h = blockIdx.x, b = blockIdx.y, c = blockIdx.z;
    int tid = threadIdx.x;
    __shared__ float qs[64];
    __shared__ float parr[256];
    __shared__ float red[256];
    __shared__ float pvred[4][64];
    if (tid < 64) {
        float qv = cbq_l[h * 64 + tid];
        for (int rc = 0; rc < 4; ++rc)
            qv += qkvp[(size_t)((rc * HH + h) * BB + b) * 64 + tid];
        qs[tid] = qv;
    }
    __syncthreads();
    int j = c * 256 + tid;
    const float* kb = ckl + ((size_t)(b * HH + h) * DHD) * TENC + j;
    float sc = 0.f;
#pragma unroll 8
    for (int dh = 0; dh < 64; ++dh)
        sc += qs[dh] * kb[(size_t)dh * TENC];
    red[tid] = sc; __syncthreads();
    for (int st = 128; st > 0; st >>= 1) { if (tid < st) red[tid] = fmaxf(red[tid], red[tid + st]); __syncthreads(); }
    float m = red[0]; __syncthreads();
    float p = expf(sc - m);
    parr[tid] = p; red[tid] = p; __syncthreads();
    for (int st = 128; st > 0; st >>= 1) { if (tid < st) red[tid] += red[tid + st]; __syncthreads(); }
    float ssum = red[0];
    int g = tid >> 6, lane = tid & 63;
    const float* vb = cvl + ((size_t)(b * HH + h) * TENC) * DHD;
    float acc = 0.f;
#pragma unroll 4
    for (int i = g; i < 256; i += 4)
        acc += parr[i] * vb[(size_t)(c * 256 + i) * DHD + lane];
    pvred[g][lane] = acc; __syncthreads();
    float* st_ = stats + (size_t)((b * HH + h) * 4 + c) * 66;
    if (tid == 0) { st_[0] = m; st_[1] = ssum; }
    if (g == 0) st_[2 + lane] = pvred[0][lane] + pvred[1][lane] + pvred[2][lane] + pvred[3][lane];
}

__global__ __launch_bounds__(64) void attn_cross_B(
    const float* __restrict__ stats, float* __restrict__ aout) {
    int h = blockIdx.x, b = blockIdx.y, lane = threadIdx.x;
    const float* st0 = stats + (size_t)((b * HH + h) * 4) * 66;
    float m0 = st0[0], m1 = st0[66];
    float M = fmaxf(m0, m1);
    float e0 = expf(m0 - M), e1 = expf(m1 - M);
    float denom = e0 * st0[1] + e1 * st0[67];
    float num = e0 * st0[2 + lane] + e1 * st0[68 + lane];
    aout[(b * HH + h) * 64 + lane] = num / denom;
}

// generic partial GEMV: outp[rc][b][col] = sum_{rows in chunk} act(b,row) * W[row*ldw+col]
// ACT_MODE 0: act = actbuf[b*K+row];  1: act = relu(abias[row] + sum_j pin[j][b][row])
template <int ACT_MODE>
__global__ __launch_bounds__(256) void gemv_part(
    const float* __restrict__ W, int ldw, int K, int N,
    const float* __restrict__ actbuf, const float* __restrict__ abias,
    const float* __restrict__ pin, int np, float* __restrict__ outp) {
    int cc = blockIdx.x, rc = blockIdx.y, R = gridDim.y, tid = threadIdx.x;
    int rows = K / R, row0 = rc * rows;
    __shared__ float acts[BB * 320];
    for (int i = tid; i < BB * rows; i += 256) {
        int b = i / rows, r = i % rows;
        float v;
        if (ACT_MODE == 0) {
            v = actbuf[(size_t)b * K + row0 + r];
        } else {
            v = abias[row0 + r];
            for (int j = 0; j < np; ++j) v += pin[(size_t)(j * BB + b) * K + row0 + r];
            v = fmaxf(v, 0.0f);
        }
        acts[b * rows + r] = v;
    }
    __syncthreads();
    int col = cc * 256 + tid;
    if (col >= N) return;
    float a0 = 0, a1 = 0, a2 = 0, a3 = 0;
    const float* Wp = W + (size_t)row0 * ldw + col;
#pragma unroll 4
    for (int r = 0; r < rows; ++r) {
        float w = Wp[(size_t)r * ldw];
        a0 += acts[r] * w;
        a1 += acts[rows + r] * w;
        a2 += acts[2 * rows + r] * w;
        a3 += acts[3 * rows + r] * w;
    }
    outp[(size_t)(rc * BB + 0) * N + col] = a0;
    outp[(size_t)(rc * BB + 1) * N + col] = a1;
    outp[(size_t)(rc * BB + 2) * N + col] = a2;
    outp[(size_t)(rc * BB + 3) * N + col] = a3;
}

__global__ __launch_bounds__(256) void proj_fin(
    const float* __restrict__ part, const float* __restrict__ pb, float* __restrict__ out) {
    int c = blockIdx.x * 256 + threadIdx.x;
    if (c < VV) {
        for (int b = 0; b < BB; ++b) {
            float v = pb[c];
            for (int rc = 0; rc < 5; ++rc) v += part[(size_t)(rc * BB + b) * VV + c];
            out[LG_OFF + (size_t)b * VV + c] = v;
        }
    }
    if (blockIdx.x == 0 && threadIdx.x == 0) out[KV_IDX] = (float)(HIST + 1);
}

// ---------------- host ----------------
extern "C" void kernel_launch(void* const* d_in, const int* in_sizes, int n_in,
                              void* d_out, int out_size, void* d_ws, size_t ws_size,
                              hipStream_t stream) {
    const float* kc    = (const float*)d_in[0];
    const float* vc    = (const float*)d_in[1];
    const float* ck    = (const float*)d_in[2];
    const float* cv    = (const float*)d_in[3];
    const int*   ids   = (const int*)d_in[4];
    const float* mflag = (const float*)d_in[7];
    const float* emb   = (const float*)d_in[8];
    const float* pe    = (const float*)d_in[9];
    const float* snw   = (const float*)d_in[10];
    const float* snb   = (const float*)d_in[11];
    const float* wq    = (const float*)d_in[12];
    const float* bq    = (const float*)d_in[13];
    const float* wk    = (const float*)d_in[14];
    const float* wv    = (const float*)d_in[15];
    const float* bv    = (const float*)d_in[16];
    const float* fcw   = (const float*)d_in[17];
    const float* fcb   = (const float*)d_in[18];
    const float* cnw   = (const float*)d_in[19];
    const float* cnb   = (const float*)d_in[20];
    const float* cwq   = (const float*)d_in[21];
    const float* cbq   = (const float*)d_in[22];
    const float* cfcw  = (const float*)d_in[23];
    const float* cfcb  = (const float*)d_in[24];
    const float* mnw   = (const float*)d_in[25];
    const float* mnb   = (const float*)d_in[26];
    const float* w1    = (const float*)d_in[27];
    const float* b1    = (const float*)d_in[28];
    const float* w2    = (const float*)d_in[29];
    const float* b2    = (const float*)d_in[30];
    const float* lnow  = (const float*)d_in[31];
    const float* lnob  = (const float*)d_in[32];
    const float* projw = (const float*)d_in[33];
    const float* projb = (const float*)d_in[34];

    float* out = (float*)d_out;
    float* ws  = (float*)d_ws;

    float* x     = ws;             // 5120
    float* xn    = ws + 5120;      // 5120
    float* qkvp  = ws + 10240;     // 61440
    float* aout  = ws + 71680;     // 5120
    float* stats = ws + 76800;     // 21120
    float* part1 = ws + 97920;     // 160000
    float* part2 = ws + 257920;    // 81920

    float* nk = out + NK_OFF;
    float* nv = out + NV_OFF;

    embed_kernel<<<20, 256, 0, stream>>>(emb, pe, ids, x);
    ln_fin<<<BB, 256, 0, stream>>>(x, nullptr, 0, nullptr, snw, snb, xn);

    for (int l = 0; l < NLAYER; ++l) {
        const float* kc_l  = kc + (size_t)l * BB * HH * DHD * HIST;
        const float* vc_l  = vc + (size_t)l * BB * HH * HIST * DHD;
        const float* ck_l  = ck + (size_t)l * BB * HH * DHD * TENC;
        const float* cv_l  = cv + (size_t)l * BB * HH * TENC * DHD;
        float* nk_l = nk + (size_t)l * BB * HH * DHD * KVLEN;
        float* nv_l = nv + (size_t)l * BB * HH * KVLEN * DHD;
        const float* wq_l   = wq + (size_t)l * HH * DD * DHD;
        const float* wk_l   = wk + (size_t)l * HH * DD * DHD;
        const float* wv_l   = wv + (size_t)l * HH * DD * DHD;
        const float* cwq_l  = cwq + (size_t)l * HH * DD * DHD;
        const float* bq_l   = bq + (size_t)l * HH * DHD;
        const float* bv_l   = bv + (size_t)l * HH * DHD;
        const float* cbq_l  = cbq + (size_t)l * HH * DHD;
        const float* fcw_l  = fcw + (size_t)l * HH * DHD * DD;
        const float* cfcw_l = cfcw + (size_t)l * HH * DHD * DD;
        const float* fcb_l  = fcb + (size_t)l * DD;
        const float* cfcb_l = cfcb + (size_t)l * DD;
        const float* w1_l   = w1 + (size_t)l * DD * DFFN;
        const float* b1_l   = b1 + (size_t)l * DFFN;
        const float* w2_l   = w2 + (size_t)l * DFFN * DD;
        const float* b2_l   = b2 + (size_t)l * DD;

        // self-attention
        qkv_part_k<<<dim3(HH, 12), 256, 0, stream>>>(wq_l, wk_l, wv_l, xn, qkvp);
        attn_self_A<<<dim3(HH, BB, 4), 256, 0, stream>>>(kc_l, vc_l, qkvp, bq_l, mflag, nk_l, nv_l, stats);
        attn_self_B<<<dim3(HH, BB), 64, 0, stream>>>(qkvp, bq_l, bv_l, mflag, stats, nk_l, nv_l, aout);
        gemv_part<0><<<dim3(5, 8), 256, 0, stream>>>(fcw_l, DD, DD, DD, aout, nullptr, nullptr, 0, part1);
        ln_fin<<<BB, 256, 0, stream>>>(x, part1, 8, fcb_l, cnw + l * DD, cnb + l * DD, xn);

        // cross-attention
        qkv_part_k<<<dim3(HH, 4), 256, 0, stream>>>(cwq_l, cwq_l, cwq_l, xn, qkvp);
        attn_cross_A<<<dim3(HH, BB, 2), 256, 0, stream>>>(ck_l, cv_l, qkvp, cbq_l, stats);
        attn_cross_B<<<dim3(HH, BB), 64, 0, stream>>>(stats, aout);
        gemv_part<0><<<dim3(5, 8), 256, 0, stream>>>(cfcw_l, DD, DD, DD, aout, nullptr, nullptr, 0, part1);
        ln_fin<<<BB, 256, 0, stream>>>(x, part1, 8, cfcb_l, mnw + l * DD, mnb + l * DD, xn);

        // FFN
        gemv_part<0><<<dim3(20, 4), 256, 0, stream>>>(w1_l, DFFN, DD, DFFN, xn, nullptr, nullptr, 0, part1);
        gemv_part<1><<<dim3(5, 16), 256, 0, stream>>>(w2_l, DD, DFFN, DD, nullptr, b1_l, part1, 4, part2);
        const float* nlw = (l < NLAYER - 1) ? snw + (l + 1) * DD : lnow;
        const float* nlb = (l < NLAYER - 1) ? snb + (l + 1) * DD : lnob;
        ln_fin<<<BB, 256, 0, stream>>>(x, part2, 16, b2_l, nlw, nlb, xn);
    }

    // final projection: h (=xn) @ proj_w + proj_b
    gemv_part<0><<<dim3(32, 5), 256, 0, stream>>>(projw, VV, DD, VV, xn, nullptr, nullptr, 0, part1);
    proj_fin<<<32, 256, 0, stream>>>(part1, projb, out);
}

// Round 4
// 2957.016 us; speedup vs baseline: 1.4468x; 1.4468x over previous
//
#include <hip/hip_runtime.h>

#define BB 4
#define HH 20
#define DHD 64
#define DD 1280
#define DFFN 5120
#define VV 8000
#define HIST 1024
#define TENC 512
#define KVLEN 1025
#define NLAYER 16

// ---------------- output offsets (floats) ----------------
static const size_t NK_OFF = 0;
static const size_t NV_OFF = 83968000ull;              // 16*4*20*64*1025
static const size_t LG_OFF = 167936000ull;
static const size_t KV_IDX = 167968000ull;

__device__ __forceinline__ void fma4(float4& a, float s, const float4& w) {
    a.x += s * w.x; a.y += s * w.y; a.z += s * w.z; a.w += s * w.w;
}

// ---------------- kernels ----------------

__global__ __launch_bounds__(256) void embed_kernel(
    const float* __restrict__ emb, const float* __restrict__ pe,
    const int* __restrict__ ids, float* __restrict__ x) {
    int i = blockIdx.x * 256 + threadIdx.x;   // B*D = 5120
    if (i >= BB * DD) return;
    int b = i / DD, d = i % DD;
    int tok = ids[b];
    x[i] = emb[(size_t)tok * DD + d] + pe[(size_t)HIST * DD + d];
}

// residual finalize (x += rbias + sum_j pin[j]) then LayerNorm -> xn.  grid=B, block=256
__global__ __launch_bounds__(256) void ln_fin(
    float* __restrict__ x, const float* __restrict__ pin, int np,
    const float* __restrict__ rbias,
    const float* __restrict__ lw, const float* __restrict__ lb,
    float* __restrict__ xn) {
    int b = blockIdx.x, tid = threadIdx.x;
    __shared__ float vbuf[DD];
    __shared__ float red[256];
    float* xb = x + b * DD;
    for (int i = tid; i < DD; i += 256) {
        float v = xb[i];
        if (rbias) v += rbias[i];
        for (int j = 0; j < np; ++j) v += pin[(size_t)(j * BB + b) * DD + i];
        xb[i] = v;
        vbuf[i] = v;
    }
    __syncthreads();
    float s = 0.f;
    for (int i = tid; i < DD; i += 256) s += vbuf[i];
    red[tid] = s; __syncthreads();
    for (int st = 128; st > 0; st >>= 1) { if (tid < st) red[tid] += red[tid + st]; __syncthreads(); }
    float mean = red[0] / DD; __syncthreads();
    float vs = 0.f;
    for (int i = tid; i < DD; i += 256) { float d = vbuf[i] - mean; vs += d * d; }
    red[tid] = vs; __syncthreads();
    for (int st = 128; st > 0; st >>= 1) { if (tid < st) red[tid] += red[tid + st]; __syncthreads(); }
    float rstd = rsqrtf(red[0] / DD + 1e-5f);
    for (int i = tid; i < DD; i += 256)
        xn[b * DD + i] = (vbuf[i] - mean) * rstd * lw[i] + lb[i];
}

// QKV partial GEMV, float4 weights.  grid=(H, nmat*4), block=256.
// out: [(mat*4+rc)][h][b][64]
__global__ __launch_bounds__(256) void qkv_part_k(
    const float* __restrict__ w0, const float* __restrict__ w1p, const float* __restrict__ w2p,
    const float* __restrict__ xn, float* __restrict__ outp) {
    int h = blockIdx.x;
    int mat = blockIdx.y >> 2, rc = blockIdx.y & 3;
    const float* W = (mat == 0 ? w0 : mat == 1 ? w1p : w2p) + (size_t)h * DD * DHD;
    int tid = threadIdx.x;
    int sg = tid >> 4;            // 16 row subgroups
    int cq = (tid & 15) * 4;      // dh col base (float4)
    __shared__ float acts[BB * 320];
    __shared__ float red[16][BB][64];   // 16KB
    int row0 = rc * 320;
    for (int i = tid; i < BB * 320; i += 256) {
        int b = i / 320, r = i % 320;
        acts[i] = xn[b * DD + row0 + r];
    }
    __syncthreads();
    float4 a0 = {0,0,0,0}, a1 = {0,0,0,0}, a2 = {0,0,0,0}, a3 = {0,0,0,0};
    const float* Wp = W + (size_t)row0 * DHD + cq;
#pragma unroll 4
    for (int it = 0; it < 20; ++it) {
        int r = sg + it * 16;
        float4 w4 = *(const float4*)(Wp + (size_t)r * DHD);
        fma4(a0, acts[r], w4);
        fma4(a1, acts[320 + r], w4);
        fma4(a2, acts[640 + r], w4);
        fma4(a3, acts[960 + r], w4);
    }
    red[sg][0][cq+0]=a0.x; red[sg][0][cq+1]=a0.y; red[sg][0][cq+2]=a0.z; red[sg][0][cq+3]=a0.w;
    red[sg][1][cq+0]=a1.x; red[sg][1][cq+1]=a1.y; red[sg][1][cq+2]=a1.z; red[sg][1][cq+3]=a1.w;
    red[sg][2][cq+0]=a2.x; red[sg][2][cq+1]=a2.y; red[sg][2][cq+2]=a2.z; red[sg][2][cq+3]=a2.w;
    red[sg][3][cq+0]=a3.x; red[sg][3][cq+1]=a3.y; red[sg][3][cq+2]=a3.z; red[sg][3][cq+3]=a3.w;
    __syncthreads();
    int b = tid >> 6, dh = tid & 63;
    float v = 0.f;
#pragma unroll
    for (int g = 0; g < 16; ++g) v += red[g][b][dh];
    outp[(size_t)(((mat * 4 + rc) * HH + h) * BB + b) * 64 + dh] = v;
}

// self-attention chunk pass + fused cache->output copy + (c==0) new-token fold.
// grid=(H,B,4) block=256.  stats[(b*H+h)*4+c] = {m, sumexp, pv[64]}
__global__ __launch_bounds__(256) void attn_self_A(
    const float* __restrict__ kc, const float* __restrict__ vc,
    const float* __restrict__ qkvp, const float* __restrict__ bq_l,
    const float* __restrict__ bv_l, const float* __restrict__ mflagp,
    float* __restrict__ nk, float* __restrict__ nv, float* __restrict__ stats) {
    int h = blockIdx.x, b = blockIdx.y, c = blockIdx.z;
    int tid = threadIdx.x;
    __shared__ float qs[64], knS[64], vnS[64];
    __shared__ float sc4[4][256];
    __shared__ float parr[256];
    __shared__ float red[256];
    __shared__ float pvred[16][64];
    __shared__ float snS;
    float flag = mflagp[0];
    if (tid < 64) {
        float qv = bq_l[h * 64 + tid];
#pragma unroll
        for (int rc = 0; rc < 4; ++rc) qv += qkvp[(size_t)((rc * HH + h) * BB + b) * 64 + tid];
        qs[tid] = qv;
    } else if (tid < 128) {
        int l2 = tid - 64;
        float kn = 0.f;
#pragma unroll
        for (int rc = 0; rc < 4; ++rc) kn += qkvp[(size_t)(((4 + rc) * HH + h) * BB + b) * 64 + l2];
        knS[l2] = kn;
        if (c == 0) nk[(size_t)((b * HH + h) * 64 + l2) * KVLEN + HIST] = kn;
    } else if (tid < 192) {
        int l2 = tid - 128;
        float vn = bv_l[h * 64 + l2];
#pragma unroll
        for (int rc = 0; rc < 4; ++rc) vn += qkvp[(size_t)(((8 + rc) * HH + h) * BB + b) * 64 + l2];
        vnS[l2] = vn;
        if (c == 0) nv[(size_t)(b * HH + h) * KVLEN * 64 + (size_t)HIST * 64 + l2] = vn;
    }
    __syncthreads();
    // K phase (float4 along j), fused copy
    int g = tid >> 6, t = tid & 63;
    int j0 = c * 256 + t * 4;
    const float* kb = kc + (size_t)(b * HH + h) * 64 * HIST;
    float* nkb = nk + (size_t)(b * HH + h) * 64 * KVLEN;
    float ax = 0, ay = 0, az = 0, aw = 0;
#pragma unroll 4
    for (int it = 0; it < 16; ++it) {
        int dh = g * 16 + it;
        float4 k4 = *(const float4*)(kb + (size_t)dh * HIST + j0);
        float* nr = nkb + (size_t)dh * KVLEN + j0;
        nr[0] = k4.x; nr[1] = k4.y; nr[2] = k4.z; nr[3] = k4.w;
        float qd = qs[dh];
        ax += qd * k4.x; ay += qd * k4.y; az += qd * k4.z; aw += qd * k4.w;
    }
    sc4[g][t*4+0] = ax; sc4[g][t*4+1] = ay; sc4[g][t*4+2] = az; sc4[g][t*4+3] = aw;
    __syncthreads();
    int j = c * 256 + tid;
    float s = sc4[0][tid] + sc4[1][tid] + sc4[2][tid] + sc4[3][tid];
    if (j != 0) s += -128.0f * flag;
    if (c == 0 && tid < 64) {   // new-token score (j=1024, always masked position)
        float pp = qs[tid] * knS[tid];
#pragma unroll
        for (int off = 32; off > 0; off >>= 1) pp += __shfl_xor(pp, off, 64);
        if (tid == 0) snS = pp + (-128.0f * flag);
    }
    red[tid] = s; __syncthreads();
    for (int st = 128; st > 0; st >>= 1) { if (tid < st) red[tid] = fmaxf(red[tid], red[tid + st]); __syncthreads(); }
    float m = red[0];
    if (c == 0) m = fmaxf(m, snS);
    __syncthreads();
    float p = expf(s - m);
    parr[tid] = p; red[tid] = p; __syncthreads();
    for (int st = 128; st > 0; st >>= 1) { if (tid < st) red[tid] += red[tid + st]; __syncthreads(); }
    float ssum = red[0];
    float en = (c == 0) ? expf(snS - m) : 0.0f;
    // V phase (float4 along dh), fused copy
    int rg = tid >> 4, dq = (tid & 15) * 4;
    const float* vb = vc + (size_t)(b * HH + h) * HIST * 64;
    float* nvb = nv + (size_t)(b * HH + h) * KVLEN * 64;
    float vx = 0, vy = 0, vz = 0, vw = 0;
#pragma unroll 4
    for (int it = 0; it < 16; ++it) {
        int i = rg + it * 16;
        size_t jj = (size_t)(c * 256 + i);
        float4 v4 = *(const float4*)(vb + jj * 64 + dq);
        *(float4*)(nvb + jj * 64 + dq) = v4;
        float pw = parr[i];
        vx += pw * v4.x; vy += pw * v4.y; vz += pw * v4.z; vw += pw * v4.w;
    }
    pvred[rg][dq+0] = vx; pvred[rg][dq+1] = vy; pvred[rg][dq+2] = vz; pvred[rg][dq+3] = vw;
    __syncthreads();
    float* st_ = stats + (size_t)((b * HH + h) * 4 + c) * 66;
    if (tid == 0) { st_[0] = m; st_[1] = ssum + en; }
    if (tid < 64) {
        float pv = 0.f;
#pragma unroll
        for (int rgi = 0; rgi < 16; ++rgi) pv += pvred[rgi][tid];
        if (c == 0) pv += en * vnS[tid];
        st_[2 + tid] = pv;
    }
}

// cross-attention chunk pass. grid=(H,B,2) block=256
__global__ __launch_bounds__(256) void attn_cross_A(
    const float* __restrict__ ck, const float* __restrict__ cv,
    const float* __restrict__ qkvp, const float* __restrict__ cbq_l,
    float* __restrict__ stats) {
    int h = blockIdx.x, b = blockIdx.y, c = blockIdx.z;
    int tid = threadIdx.x;
    __shared__ float qs[64];
    __shared__ float sc4[4][256];
    __shared__ float parr[256];
    __shared__ float red[256];
    __shared__ float pvred[16][64];
    if (tid < 64) {
        float qv = cbq_l[h * 64 + tid];
#pragma unroll
        for (int rc = 0; rc < 4; ++rc) qv += qkvp[(size_t)((rc * HH + h) * BB + b) * 64 + tid];
        qs[tid] = qv;
    }
    __syncthreads();
    int g = tid >> 6, t = tid & 63;
    int j0 = c * 256 + t * 4;
    const float* kb = ck + (size_t)(b * HH + h) * 64 * TENC;
    float ax = 0, ay = 0, az = 0, aw = 0;
#pragma unroll 4
    for (int it = 0; it < 16; ++it) {
        int dh = g * 16 + it;
        float4 k4 = *(const float4*)(kb + (size_t)dh * TENC + j0);
        float qd = qs[dh];
        ax += qd * k4.x; ay += qd * k4.y; az += qd * k4.z; aw += qd * k4.w;
    }
    sc4[g][t*4+0] = ax; sc4[g][t*4+1] = ay; sc4[g][t*4+2] = az; sc4[g][t*4+3] = aw;
    __syncthreads();
    float s = sc4[0][tid] + sc4[1][tid] + sc4[2][tid] + sc4[3][tid];
    red[tid] = s; __syncthreads();
    for (int st = 128; st > 0; st >>= 1) { if (tid < st) red[tid] = fmaxf(red[tid], red[tid + st]); __syncthreads(); }
    float m = red[0]; __syncthreads();
    float p = expf(s - m);
    parr[tid] = p; red[tid] = p; __syncthreads();
    for (int st = 128; st > 0; st >>= 1) { if (tid < st) red[tid] += red[tid + st]; __syncthreads(); }
    float ssum = red[0];
    int rg = tid >> 4, dq = (tid & 15) * 4;
    const float* vb = cv + (size_t)(b * HH + h) * TENC * 64;
    float vx = 0, vy = 0, vz = 0, vw = 0;
#pragma unroll 4
    for (int it = 0; it < 16; ++it) {
        int i = rg + it * 16;
        size_t jj = (size_t)(c * 256 + i);
        float4 v4 = *(const float4*)(vb + jj * 64 + dq);
        float pw = parr[i];
        vx += pw * v4.x; vy += pw * v4.y; vz += pw * v4.z; vw += pw * v4.w;
    }
    pvred[rg][dq+0] = vx; pvred[rg][dq+1] = vy; pvred[rg][dq+2] = vz; pvred[rg][dq+3] = vw;
    __syncthreads();
    float* st_ = stats + (size_t)((b * HH + h) * 4 + c) * 66;
    if (tid == 0) { st_[0] = m; st_[1] = ssum; }
    if (tid < 64) {
        float pv = 0.f;
#pragma unroll
        for (int rgi = 0; rgi < 16; ++rgi) pv += pvred[rgi][tid];
        st_[2 + tid] = pv;
    }
}

// generic partial GEMV, float4 weights. grid=(ceil(N/256), R), block=256.
// ACT_MODE 0: act = actbuf[b*K+row]
// ACT_MODE 1: act = relu(abias[row] + sum_j pin[j][b][row])
// ACT_MODE 2: act = attention chunk-merge from stats (nc chunks)
template <int ACT_MODE>
__global__ __launch_bounds__(256) void gemv_part(
    const float* __restrict__ W, int ldw, int K, int N,
    const float* __restrict__ actbuf, const float* __restrict__ abias,
    const float* __restrict__ pin, int np,
    const float* __restrict__ stats, int nc,
    float* __restrict__ outp) {
    int cc = blockIdx.x, rc = blockIdx.y, R = gridDim.y, tid = threadIdx.x;
    int rows = K / R, row0 = rc * rows;
    int sg = tid >> 6, t = tid & 63;
    __shared__ float acts[BB * 320];
    __shared__ float red[4][BB][256];   // 16KB
    for (int i = tid; i < BB * rows; i += 256) {
        int b = i / rows, r = i % rows;
        float v;
        if (ACT_MODE == 0) {
            v = actbuf[(size_t)b * K + row0 + r];
        } else if (ACT_MODE == 1) {
            v = abias[row0 + r];
            for (int j = 0; j < np; ++j) v += pin[(size_t)(j * BB + b) * K + row0 + r];
            v = fmaxf(v, 0.0f);
        } else {
            int gr = row0 + r;
            int hh = gr >> 6, dh = gr & 63;
            const float* st = stats + (size_t)((b * HH + hh) * 4) * 66;
            float M = st[0];
            for (int cI = 1; cI < nc; ++cI) M = fmaxf(M, st[cI * 66]);
            float den = 0.f, num = 0.f;
            for (int cI = 0; cI < nc; ++cI) {
                float e = expf(st[cI * 66] - M);
                den += e * st[cI * 66 + 1];
                num += e * st[cI * 66 + 2 + dh];
            }
            v = num / den;
        }
        acts[b * rows + r] = v;
    }
    __syncthreads();
    int col = cc * 256 + t * 4;
    float4 a0 = {0,0,0,0}, a1 = {0,0,0,0}, a2 = {0,0,0,0}, a3 = {0,0,0,0};
    if (col < N) {
        const float* Wp = W + (size_t)row0 * ldw + col;
#pragma unroll 4
        for (int r = sg; r < rows; r += 4) {
            float4 w4 = *(const float4*)(Wp + (size_t)r * ldw);
            fma4(a0, acts[r], w4);
            fma4(a1, acts[rows + r], w4);
            fma4(a2, acts[2 * rows + r], w4);
            fma4(a3, acts[3 * rows + r], w4);
        }
    }
    red[sg][0][t*4+0]=a0.x; red[sg][0][t*4+1]=a0.y; red[sg][0][t*4+2]=a0.z; red[sg][0][t*4+3]=a0.w;
    red[sg][1][t*4+0]=a1.x; red[sg][1][t*4+1]=a1.y; red[sg][1][t*4+2]=a1.z; red[sg][1][t*4+3]=a1.w;
    red[sg][2][t*4+0]=a2.x; red[sg][2][t*4+1]=a2.y; red[sg][2][t*4+2]=a2.z; red[sg][2][t*4+3]=a2.w;
    red[sg][3][t*4+0]=a3.x; red[sg][3][t*4+1]=a3.y; red[sg][3][t*4+2]=a3.z; red[sg][3][t*4+3]=a3.w;
    __syncthreads();
    int b = tid >> 6, t2 = tid & 63;
    int col2 = cc * 256 + t2 * 4;
    if (col2 < N) {
        float4 o;
        o.x = red[0][b][t2*4+0] + red[1][b][t2*4+0] + red[2][b][t2*4+0] + red[3][b][t2*4+0];
        o.y = red[0][b][t2*4+1] + red[1][b][t2*4+1] + red[2][b][t2*4+1] + red[3][b][t2*4+1];
        o.z = red[0][b][t2*4+2] + red[1][b][t2*4+2] + red[2][b][t2*4+2] + red[3][b][t2*4+2];
        o.w = red[0][b][t2*4+3] + red[1][b][t2*4+3] + red[2][b][t2*4+3] + red[3][b][t2*4+3];
        *(float4*)(outp + (size_t)(rc * BB + b) * N + col2) = o;
    }
}

__global__ __launch_bounds__(256) void proj_fin(
    const float* __restrict__ part, const float* __restrict__ pb, float* __restrict__ out) {
    int c = blockIdx.x * 256 + threadIdx.x;
    if (c < VV) {
        for (int b = 0; b < BB; ++b) {
            float v = pb[c];
            for (int rc = 0; rc < 8; ++rc) v += part[(size_t)(rc * BB + b) * VV + c];
            out[LG_OFF + (size_t)b * VV + c] = v;
        }
    }
    if (blockIdx.x == 0 && threadIdx.x == 0) out[KV_IDX] = (float)(HIST + 1);
}

// ---------------- host ----------------
extern "C" void kernel_launch(void* const* d_in, const int* in_sizes, int n_in,
                              void* d_out, int out_size, void* d_ws, size_t ws_size,
                              hipStream_t stream) {
    const float* kc    = (const float*)d_in[0];
    const float* vc    = (const float*)d_in[1];
    const float* ck    = (const float*)d_in[2];
    const float* cv    = (const float*)d_in[3];
    const int*   ids   = (const int*)d_in[4];
    const float* mflag = (const float*)d_in[7];
    const float* emb   = (const float*)d_in[8];
    const float* pe    = (const float*)d_in[9];
    const float* snw   = (const float*)d_in[10];
    const float* snb   = (const float*)d_in[11];
    const float* wq    = (const float*)d_in[12];
    const float* bq    = (const float*)d_in[13];
    const float* wk    = (const float*)d_in[14];
    const float* wv    = (const float*)d_in[15];
    const float* bv    = (const float*)d_in[16];
    const float* fcw   = (const float*)d_in[17];
    const float* fcb   = (const float*)d_in[18];
    const float* cnw   = (const float*)d_in[19];
    const float* cnb   = (const float*)d_in[20];
    const float* cwq   = (const float*)d_in[21];
    const float* cbq   = (const float*)d_in[22];
    const float* cfcw  = (const float*)d_in[23];
    const float* cfcb  = (const float*)d_in[24];
    const float* mnw   = (const float*)d_in[25];
    const float* mnb   = (const float*)d_in[26];
    const float* w1    = (const float*)d_in[27];
    const float* b1    = (const float*)d_in[28];
    const float* w2    = (const float*)d_in[29];
    const float* b2    = (const float*)d_in[30];
    const float* lnow  = (const float*)d_in[31];
    const float* lnob  = (const float*)d_in[32];
    const float* projw = (const float*)d_in[33];
    const float* projb = (const float*)d_in[34];

    float* out = (float*)d_out;
    float* ws  = (float*)d_ws;

    float* x     = ws;              // 5120
    float* xn    = ws + 5120;       // 5120
    float* qkvp  = ws + 10240;      // 61440
    float* stats = ws + 71680;      // 21120
    float* part1 = ws + 92800;      // 327680
    float* part2 = ws + 420480;     // 81920

    float* nk = out + NK_OFF;
    float* nv = out + NV_OFF;

    embed_kernel<<<20, 256, 0, stream>>>(emb, pe, ids, x);
    ln_fin<<<BB, 256, 0, stream>>>(x, nullptr, 0, nullptr, snw, snb, xn);

    for (int l = 0; l < NLAYER; ++l) {
        const float* kc_l  = kc + (size_t)l * BB * HH * DHD * HIST;
        const float* vc_l  = vc + (size_t)l * BB * HH * HIST * DHD;
        const float* ck_l  = ck + (size_t)l * BB * HH * DHD * TENC;
        const float* cv_l  = cv + (size_t)l * BB * HH * TENC * DHD;
        float* nk_l = nk + (size_t)l * BB * HH * DHD * KVLEN;
        float* nv_l = nv + (size_t)l * BB * HH * KVLEN * DHD;
        const float* wq_l   = wq + (size_t)l * HH * DD * DHD;
        const float* wk_l   = wk + (size_t)l * HH * DD * DHD;
        const float* wv_l   = wv + (size_t)l * HH * DD * DHD;
        const float* cwq_l  = cwq + (size_t)l * HH * DD * DHD;
        const float* bq_l   = bq + (size_t)l * HH * DHD;
        const float* bv_l   = bv + (size_t)l * HH * DHD;
        const float* cbq_l  = cbq + (size_t)l * HH * DHD;
        const float* fcw_l  = fcw + (size_t)l * HH * DHD * DD;
        const float* cfcw_l = cfcw + (size_t)l * HH * DHD * DD;
        const float* fcb_l  = fcb + (size_t)l * DD;
        const float* cfcb_l = cfcb + (size_t)l * DD;
        const float* w1_l   = w1 + (size_t)l * DD * DFFN;
        const float* b1_l   = b1 + (size_t)l * DFFN;
        const float* w2_l   = w2 + (size_t)l * DFFN * DD;
        const float* b2_l   = b2 + (size_t)l * DD;

        // self-attention (new-token fold inside attn_self_A; merge inside fc gemv)
        qkv_part_k<<<dim3(HH, 12), 256, 0, stream>>>(wq_l, wk_l, wv_l, xn, qkvp);
        attn_self_A<<<dim3(HH, BB, 4), 256, 0, stream>>>(kc_l, vc_l, qkvp, bq_l, bv_l, mflag, nk_l, nv_l, stats);
        gemv_part<2><<<dim3(5, 16), 256, 0, stream>>>(fcw_l, DD, DD, DD, nullptr, nullptr, nullptr, 0, stats, 4, part2);
        ln_fin<<<BB, 256, 0, stream>>>(x, part2, 16, fcb_l, cnw + l * DD, cnb + l * DD, xn);

        // cross-attention
        qkv_part_k<<<dim3(HH, 4), 256, 0, stream>>>(cwq_l, cwq_l, cwq_l, xn, qkvp);
        attn_cross_A<<<dim3(HH, BB, 2), 256, 0, stream>>>(ck_l, cv_l, qkvp, cbq_l, stats);
        gemv_part<2><<<dim3(5, 16), 256, 0, stream>>>(cfcw_l, DD, DD, DD, nullptr, nullptr, nullptr, 0, stats, 2, part2);
        ln_fin<<<BB, 256, 0, stream>>>(x, part2, 16, cfcb_l, mnw + l * DD, mnb + l * DD, xn);

        // FFN
        gemv_part<0><<<dim3(20, 16), 256, 0, stream>>>(w1_l, DFFN, DD, DFFN, xn, nullptr, nullptr, 0, nullptr, 0, part1);
        gemv_part<1><<<dim3(5, 16), 256, 0, stream>>>(w2_l, DD, DFFN, DD, nullptr, b1_l, part1, 16, nullptr, 0, part2);
        const float* nlw = (l < NLAYER - 1) ? snw + (l + 1) * DD : lnow;
        const float* nlb = (l < NLAYER - 1) ? snb + (l + 1) * DD : lnob;
        ln_fin<<<BB, 256, 0, stream>>>(x, part2, 16, b2_l, nlw, nlb, xn);
    }

    // final projection: h (=xn) @ proj_w + proj_b
    gemv_part<0><<<dim3(32, 8), 256, 0, stream>>>(projw, VV, DD, VV, xn, nullptr, nullptr, 0, nullptr, 0, part1);
    proj_fin<<<32, 256, 0, stream>>>(part1, projb, out);
}